// Round 1
// baseline (219.826 us; speedup 1.0000x reference)
//
#include <hip/hip_runtime.h>
#include <hip/hip_bf16.h>

#define B_  8
#define T_  2048
#define C_  1024
#define H_  128

using f32x4  = __attribute__((ext_vector_type(4))) float;
using bf16x8 = __attribute__((ext_vector_type(8))) short;

__device__ __forceinline__ unsigned short f2bf(float f) {
    union { float f; unsigned u; } v; v.f = f;
    unsigned r = v.u + 0x7FFFu + ((v.u >> 16) & 1u);   // RNE
    return (unsigned short)(r >> 16);
}
__device__ __forceinline__ float bf2f(unsigned short s) {
    union { unsigned u; float f; } v; v.u = ((unsigned)s) << 16;
    return v.f;
}

// ---------------------------------------------------------------------------
// Kernel 1: convert W{q,k,v} fp32 [1024][128] -> Wt bf16 [384 cols][1024 k]
// (transposed so GEMM B-fragments are contiguous 16B loads)
// ---------------------------------------------------------------------------
__global__ void wconv_kernel(const float* __restrict__ Wq,
                             const float* __restrict__ Wk,
                             const float* __restrict__ Wv,
                             unsigned short* __restrict__ Wt) {
    int id  = blockIdx.x * 256 + threadIdx.x;          // 0 .. 384*1024-1
    int col = id % 384;
    int k   = id / 384;
    const float* W = (col < 128) ? Wq : ((col < 256) ? Wk : Wv);
    float v = W[k * H_ + (col & 127)];
    Wt[(size_t)col * C_ + k] = f2bf(v);
}

// ---------------------------------------------------------------------------
// Kernel 2: fused projection. Block = 256 thr (4 waves), tile 64 rows x 384 cols.
// Wave w handles all 64 rows x cols [96w, 96w+96). No LDS; A converted on the fly.
// Outputs: qb,kb row-major [16384][128] bf16; v stored transposed vT [8][128][2048].
// ---------------------------------------------------------------------------
__launch_bounds__(256)
__global__ void proj_kernel(const float* __restrict__ x,
                            const unsigned short* __restrict__ Wt,
                            unsigned short* __restrict__ qb,
                            unsigned short* __restrict__ kb,
                            unsigned short* __restrict__ vT) {
    const int wave = threadIdx.x >> 6;
    const int lane = threadIdx.x & 63;
    const int lo = lane & 15, hi = lane >> 4;
    const int row0 = blockIdx.x * 64;
    const int col0 = wave * 96;

    f32x4 acc[4][6];
    #pragma unroll
    for (int rt = 0; rt < 4; ++rt)
        #pragma unroll
        for (int ct = 0; ct < 6; ++ct)
            acc[rt][ct] = f32x4{0.f, 0.f, 0.f, 0.f};

    for (int kk = 0; kk < C_; kk += 32) {
        bf16x8 a[4];
        #pragma unroll
        for (int rt = 0; rt < 4; ++rt) {
            const float* xp = x + (size_t)(row0 + rt * 16 + lo) * C_ + kk + 8 * hi;
            float4 f0 = *(const float4*)xp;
            float4 f1 = *(const float4*)(xp + 4);
            bf16x8 av;
            av[0] = (short)f2bf(f0.x); av[1] = (short)f2bf(f0.y);
            av[2] = (short)f2bf(f0.z); av[3] = (short)f2bf(f0.w);
            av[4] = (short)f2bf(f1.x); av[5] = (short)f2bf(f1.y);
            av[6] = (short)f2bf(f1.z); av[7] = (short)f2bf(f1.w);
            a[rt] = av;
        }
        #pragma unroll
        for (int ct = 0; ct < 6; ++ct) {
            const unsigned short* wp = Wt + (size_t)(col0 + ct * 16 + lo) * C_ + kk + 8 * hi;
            bf16x8 bfr = *(const bf16x8*)wp;
            #pragma unroll
            for (int rt = 0; rt < 4; ++rt)
                acc[rt][ct] = __builtin_amdgcn_mfma_f32_16x16x32_bf16(a[rt], bfr, acc[rt][ct], 0, 0, 0);
        }
    }

    // Epilogue: D layout col = lane&15, row = 4*(lane>>4)+reg
    #pragma unroll
    for (int ct = 0; ct < 6; ++ct) {
        int col = col0 + ct * 16 + lo;
        int head = col >> 7;       // 0=q 1=k 2=v
        int h = col & 127;
        #pragma unroll
        for (int rt = 0; rt < 4; ++rt) {
            #pragma unroll
            for (int r = 0; r < 4; ++r) {
                int rg = row0 + rt * 16 + 4 * hi + r;
                unsigned short val = f2bf(acc[rt][ct][r]);
                if (head == 0)      qb[(size_t)rg * H_ + h] = val;
                else if (head == 1) kb[(size_t)rg * H_ + h] = val;
                else {
                    int b = rg >> 11, t = rg & (T_ - 1);
                    vT[((size_t)b * H_ + h) * T_ + t] = val;
                }
            }
        }
    }
}

// ---------------------------------------------------------------------------
// Kernel 3: causal flash attention. Block = 128 thr (2 waves), QBLK=32 (16 q/wave),
// KVBLK=32. Grid = 8 batches * 64 q-tiles, heavy-tile-first remap.
// ---------------------------------------------------------------------------
__launch_bounds__(128)
__global__ void attn_kernel(const unsigned short* __restrict__ qb,
                            const unsigned short* __restrict__ kb,
                            const unsigned short* __restrict__ vT,
                            float* __restrict__ out) {
    __shared__ unsigned short Ks[32][136];   // K rows, padded (+8)
    __shared__ unsigned short Vs[128][40];   // V^T rows (h-major), padded (+8)
    __shared__ unsigned short Ps[2][16][40]; // per-wave P transpose buffer

    const int tid  = threadIdx.x;
    const int wave = tid >> 6;
    const int lane = tid & 63;
    const int lo = lane & 15, hi = lane >> 4;

    const int bid = blockIdx.x;
    const int b   = bid & 7;
    const int qt  = 63 - (bid >> 3);           // heavy tiles dispatch first
    const size_t bT = (size_t)b * T_;
    const int qrow0 = qt * 32 + wave * 16;     // wave's q rows: qrow0 + (0..15)

    // Q fragments, pre-scaled by C^-0.5 = 1/32 (exact power of 2)
    bf16x8 qf[4];
    #pragma unroll
    for (int kc = 0; kc < 4; ++kc) {
        bf16x8 raw = *(const bf16x8*)(qb + (bT + qrow0 + lo) * H_ + kc * 32 + 8 * hi);
        bf16x8 s;
        #pragma unroll
        for (int j = 0; j < 8; ++j)
            s[j] = (short)f2bf(bf2f((unsigned short)raw[j]) * 0.03125f);
        qf[kc] = s;
    }

    float m[4], l[4];
    f32x4 o[8];
    #pragma unroll
    for (int r = 0; r < 4; ++r) { m[r] = -1e30f; l[r] = 0.f; }
    #pragma unroll
    for (int ct = 0; ct < 8; ++ct) o[ct] = f32x4{0.f, 0.f, 0.f, 0.f};

    for (int kt = 0; kt <= qt; ++kt) {
        const int kv0 = kt * 32;
        __syncthreads();   // previous iter done with Ks/Vs
        {   // stage K tile: 32 rows x 128 bf16 (4 threads/row, 64B each)
            int kr = tid >> 2, kc = (tid & 3) * 32;
            const uint4* src = (const uint4*)(kb + (bT + kv0 + kr) * H_ + kc);
            uint4* dst = (uint4*)(&Ks[kr][kc]);
            dst[0] = src[0]; dst[1] = src[1]; dst[2] = src[2]; dst[3] = src[3];
        }
        {   // stage V^T tile: 128 h-rows x 32 bf16 (1 thread/row, 64B)
            const uint4* src = (const uint4*)(vT + ((size_t)b * H_ + tid) * T_ + kv0);
            uint4* dst = (uint4*)(&Vs[tid][0]);
            dst[0] = src[0]; dst[1] = src[1]; dst[2] = src[2]; dst[3] = src[3];
        }
        __syncthreads();

        // S = Q K^T  (two 16-col tiles)
        f32x4 s0 = f32x4{0.f, 0.f, 0.f, 0.f}, s1 = f32x4{0.f, 0.f, 0.f, 0.f};
        #pragma unroll
        for (int kc = 0; kc < 4; ++kc) {
            bf16x8 b0 = *(const bf16x8*)(&Ks[lo][kc * 32 + 8 * hi]);
            bf16x8 b1 = *(const bf16x8*)(&Ks[16 + lo][kc * 32 + 8 * hi]);
            s0 = __builtin_amdgcn_mfma_f32_16x16x32_bf16(qf[kc], b0, s0, 0, 0, 0);
            s1 = __builtin_amdgcn_mfma_f32_16x16x32_bf16(qf[kc], b1, s1, 0, 0, 0);
        }
        // causal mask (only the diagonal tile needs it)
        if (kt == qt) {
            #pragma unroll
            for (int r = 0; r < 4; ++r) {
                int q = qrow0 + 4 * hi + r;
                if (kv0 + lo > q)      s0[r] = -1e30f;
                if (kv0 + 16 + lo > q) s1[r] = -1e30f;
            }
        }

        // online softmax (rows live in 16-lane groups)
        float pm[4];
        #pragma unroll
        for (int r = 0; r < 4; ++r) pm[r] = fmaxf(s0[r], s1[r]);
        #pragma unroll
        for (int off = 1; off < 16; off <<= 1) {
            #pragma unroll
            for (int r = 0; r < 4; ++r)
                pm[r] = fmaxf(pm[r], __shfl_xor(pm[r], off, 64));
        }
        float alpha[4], rs[4];
        #pragma unroll
        for (int r = 0; r < 4; ++r) {
            float mn = fmaxf(m[r], pm[r]);
            alpha[r] = __expf(m[r] - mn);
            m[r] = mn;
            s0[r] = __expf(s0[r] - mn);
            s1[r] = __expf(s1[r] - mn);
            rs[r] = s0[r] + s1[r];
        }
        #pragma unroll
        for (int off = 1; off < 16; off <<= 1) {
            #pragma unroll
            for (int r = 0; r < 4; ++r)
                rs[r] += __shfl_xor(rs[r], off, 64);
        }
        #pragma unroll
        for (int r = 0; r < 4; ++r) l[r] = l[r] * alpha[r] + rs[r];
        #pragma unroll
        for (int ct = 0; ct < 8; ++ct)
            #pragma unroll
            for (int r = 0; r < 4; ++r) o[ct][r] *= alpha[r];

        // P -> bf16, transpose via per-wave LDS into A-fragment layout
        #pragma unroll
        for (int r = 0; r < 4; ++r) {
            Ps[wave][4 * hi + r][lo]      = f2bf(s0[r]);
            Ps[wave][4 * hi + r][16 + lo] = f2bf(s1[r]);
        }
        __syncthreads();

        bf16x8 pa = *(const bf16x8*)(&Ps[wave][lo][8 * hi]);
        #pragma unroll
        for (int ct = 0; ct < 8; ++ct) {
            bf16x8 bv = *(const bf16x8*)(&Vs[ct * 16 + lo][8 * hi]);
            o[ct] = __builtin_amdgcn_mfma_f32_16x16x32_bf16(pa, bv, o[ct], 0, 0, 0);
        }
    }

    // epilogue: normalize and store fp32
    #pragma unroll
    for (int r = 0; r < 4; ++r) {
        float inv = 1.f / l[r];
        int q = qrow0 + 4 * hi + r;
        float* op = out + (bT + q) * H_;
        #pragma unroll
        for (int ct = 0; ct < 8; ++ct)
            op[ct * 16 + lo] = o[ct][r] * inv;
    }
}

extern "C" void kernel_launch(void* const* d_in, const int* in_sizes, int n_in,
                              void* d_out, int out_size, void* d_ws, size_t ws_size,
                              hipStream_t stream) {
    const float* x  = (const float*)d_in[0];
    const float* Wq = (const float*)d_in[1];
    const float* Wk = (const float*)d_in[2];
    const float* Wv = (const float*)d_in[3];
    float* out = (float*)d_out;

    char* ws = (char*)d_ws;
    unsigned short* Wt = (unsigned short*)ws;                       // 384*1024*2 B
    unsigned short* qbf = (unsigned short*)(ws + 384 * 1024 * 2);   // 16384*128*2 B
    unsigned short* kbf = qbf + (size_t)B_ * T_ * H_;
    unsigned short* vTf = kbf + (size_t)B_ * T_ * H_;

    wconv_kernel<<<(384 * 1024) / 256, 256, 0, stream>>>(Wq, Wk, Wv, Wt);
    proj_kernel<<<(B_ * T_) / 64, 256, 0, stream>>>(x, Wt, qbf, kbf, vTf);
    attn_kernel<<<B_ * (T_ / 32), 128, 0, stream>>>(qbf, kbf, vTf, out);
}

// Round 2
// 201.572 us; speedup vs baseline: 1.0906x; 1.0906x over previous
//
#include <hip/hip_runtime.h>
#include <hip/hip_bf16.h>

#define B_  8
#define T_  2048
#define C_  1024
#define H_  128

using f32x4  = __attribute__((ext_vector_type(4))) float;
using bf16x8 = __attribute__((ext_vector_type(8))) short;

__device__ __forceinline__ unsigned short f2bf(float f) {
    union { float f; unsigned u; } v; v.f = f;
    unsigned r = v.u + 0x7FFFu + ((v.u >> 16) & 1u);   // RNE
    return (unsigned short)(r >> 16);
}

// prefix(qt) = sum_{v=1}^{qt} ceil(v/8)  (chunk-slot prefix sum)
__device__ __forceinline__ int slot_prefix(int qt) {
    int g = qt >> 3, r = qt & 7;
    return 4 * g * (g + 1) + r * (g + 1);
}

// ---------------------------------------------------------------------------
// x fp32 [16384][1024] -> bf16
// ---------------------------------------------------------------------------
__global__ void xconv_kernel(const float* __restrict__ x,
                             unsigned short* __restrict__ xb) {
    size_t id = (size_t)blockIdx.x * 256 + threadIdx.x;   // 2M threads, 8 elems each
    const float4* xp = (const float4*)(x + id * 8);
    float4 f0 = xp[0], f1 = xp[1];
    bf16x8 v;
    v[0] = (short)f2bf(f0.x); v[1] = (short)f2bf(f0.y);
    v[2] = (short)f2bf(f0.z); v[3] = (short)f2bf(f0.w);
    v[4] = (short)f2bf(f1.x); v[5] = (short)f2bf(f1.y);
    v[6] = (short)f2bf(f1.z); v[7] = (short)f2bf(f1.w);
    *(bf16x8*)(xb + id * 8) = v;
}

// ---------------------------------------------------------------------------
// W{q,k,v} fp32 [1024][128] -> Wt bf16 [384 cols][1024 k], Wq pre-scaled 1/32
// ---------------------------------------------------------------------------
__global__ void wconv_kernel(const float* __restrict__ Wq,
                             const float* __restrict__ Wk,
                             const float* __restrict__ Wv,
                             unsigned short* __restrict__ Wt) {
    int id  = blockIdx.x * 256 + threadIdx.x;
    int col = id % 384;
    int k   = id / 384;
    const float* W = (col < 128) ? Wq : ((col < 256) ? Wk : Wv);
    float v = W[k * H_ + (col & 127)];
    if (col < 128) v *= 0.03125f;   // fold C^-0.5 into Wq (exact pow2)
    Wt[(size_t)col * C_ + k] = f2bf(v);
}

// ---------------------------------------------------------------------------
// GEMM: xb[16384][1024] @ Wt^T -> qb,kb row-major bf16; v transposed vT[8][128][2048]
// Block 256 thr (2x2 waves), tile 64 rows x 96 cols. Grid 256x4 = 1024 blocks.
// ---------------------------------------------------------------------------
__launch_bounds__(256)
__global__ void gemm_kernel(const unsigned short* __restrict__ xb,
                            const unsigned short* __restrict__ Wt,
                            unsigned short* __restrict__ qb,
                            unsigned short* __restrict__ kb,
                            unsigned short* __restrict__ vT) {
    const int wave = threadIdx.x >> 6;
    const int lane = threadIdx.x & 63;
    const int lo = lane & 15, hi = lane >> 4;
    const int rb = blockIdx.x >> 2, cb = blockIdx.x & 3;
    const int row0 = rb * 64 + (wave >> 1) * 32;
    const int col0 = cb * 96 + (wave & 1) * 48;

    f32x4 acc[2][3];
    #pragma unroll
    for (int rt = 0; rt < 2; ++rt)
        #pragma unroll
        for (int ct = 0; ct < 3; ++ct)
            acc[rt][ct] = f32x4{0.f, 0.f, 0.f, 0.f};

    for (int kk = 0; kk < C_; kk += 32) {
        bf16x8 a[2], bfr[3];
        #pragma unroll
        for (int rt = 0; rt < 2; ++rt)
            a[rt] = *(const bf16x8*)(xb + (size_t)(row0 + rt * 16 + lo) * C_ + kk + 8 * hi);
        #pragma unroll
        for (int ct = 0; ct < 3; ++ct)
            bfr[ct] = *(const bf16x8*)(Wt + (size_t)(col0 + ct * 16 + lo) * C_ + kk + 8 * hi);
        #pragma unroll
        for (int rt = 0; rt < 2; ++rt)
            #pragma unroll
            for (int ct = 0; ct < 3; ++ct)
                acc[rt][ct] = __builtin_amdgcn_mfma_f32_16x16x32_bf16(a[rt], bfr[ct], acc[rt][ct], 0, 0, 0);
    }

    #pragma unroll
    for (int ct = 0; ct < 3; ++ct) {
        int col = col0 + ct * 16 + lo;
        int head = col >> 7;
        int h = col & 127;
        #pragma unroll
        for (int rt = 0; rt < 2; ++rt) {
            #pragma unroll
            for (int r = 0; r < 4; ++r) {
                int rg = row0 + rt * 16 + 4 * hi + r;
                unsigned short val = f2bf(acc[rt][ct][r]);
                if (head == 0)      qb[(size_t)rg * H_ + h] = val;
                else if (head == 1) kb[(size_t)rg * H_ + h] = val;
                else {
                    int b = rg >> 11, t = rg & (T_ - 1);
                    vT[((size_t)b * H_ + h) * T_ + t] = val;
                }
            }
        }
    }
}

// ---------------------------------------------------------------------------
// Flash pass 1: grid 8 b x 64 qt x 8 chunk (empties exit). Block = 2 waves,
// wave owns 16 q-rows. Chunk = 256 kv (4 x KV64 tiles). No block barriers:
// K/V read direct from global (L2-resident; b=bid&7 pins batch->XCD),
// P transposed via per-wave LDS. Partial (m,l,O) -> workspace.
// ---------------------------------------------------------------------------
__launch_bounds__(128)
__global__ void attn1_kernel(const unsigned short* __restrict__ qb,
                             const unsigned short* __restrict__ kb,
                             const unsigned short* __restrict__ vT,
                             float* __restrict__ Opart,
                             float* __restrict__ MLpart) {
    __shared__ unsigned short Ps[2][16][72];

    const int tid  = threadIdx.x;
    const int wave = tid >> 6;
    const int lane = tid & 63;
    const int lo = lane & 15, hi = lane >> 4;

    const int bid   = blockIdx.x;
    const int b     = bid & 7;
    const int rest  = bid >> 3;
    const int qt    = rest & 63;
    const int chunk = rest >> 6;
    const int nch   = (qt >> 3) + 1;
    if (chunk >= nch) return;

    const int kv_begin = chunk << 8;
    const int lim      = min(kv_begin + 256, (qt + 1) << 5);
    const int ntiles   = (lim - kv_begin + 63) >> 6;
    const size_t bT    = (size_t)b * T_;
    const int qrow0    = (qt << 5) + wave * 16;

    bf16x8 qf[4];
    #pragma unroll
    for (int kc = 0; kc < 4; ++kc)
        qf[kc] = *(const bf16x8*)(qb + (bT + qrow0 + lo) * H_ + kc * 32 + 8 * hi);

    float m[4], l[4];
    f32x4 o[8];
    #pragma unroll
    for (int r = 0; r < 4; ++r) { m[r] = -1e30f; l[r] = 0.f; }
    #pragma unroll
    for (int ct = 0; ct < 8; ++ct) o[ct] = f32x4{0.f, 0.f, 0.f, 0.f};

    for (int t = 0; t < ntiles; ++t) {
        const int kv0 = kv_begin + t * 64;

        // S = Q K^T : 4 col-tiles of 16 kv
        f32x4 s[4];
        #pragma unroll
        for (int ct4 = 0; ct4 < 4; ++ct4) s[ct4] = f32x4{0.f, 0.f, 0.f, 0.f};
        #pragma unroll
        for (int ct4 = 0; ct4 < 4; ++ct4) {
            const unsigned short* kp = kb + (bT + kv0 + ct4 * 16 + lo) * H_ + 8 * hi;
            #pragma unroll
            for (int kc = 0; kc < 4; ++kc) {
                bf16x8 bk = *(const bf16x8*)(kp + kc * 32);
                s[ct4] = __builtin_amdgcn_mfma_f32_16x16x32_bf16(qf[kc], bk, s[ct4], 0, 0, 0);
            }
        }

        if (kv0 + 63 >= qrow0) {   // tile overlaps this wave's diagonal
            #pragma unroll
            for (int ct4 = 0; ct4 < 4; ++ct4)
                #pragma unroll
                for (int r = 0; r < 4; ++r)
                    if (kv0 + ct4 * 16 + lo > qrow0 + 4 * hi + r) s[ct4][r] = -1e30f;
        }

        // online softmax: rows live across lo within each 16-lane group
        float pm[4], alpha[4], rs[4];
        #pragma unroll
        for (int r = 0; r < 4; ++r)
            pm[r] = fmaxf(fmaxf(s[0][r], s[1][r]), fmaxf(s[2][r], s[3][r]));
        #pragma unroll
        for (int off = 1; off < 16; off <<= 1)
            #pragma unroll
            for (int r = 0; r < 4; ++r)
                pm[r] = fmaxf(pm[r], __shfl_xor(pm[r], off, 64));
        #pragma unroll
        for (int r = 0; r < 4; ++r) {
            float mn = fmaxf(m[r], pm[r]);
            alpha[r] = __expf(m[r] - mn);
            m[r] = mn;
            #pragma unroll
            for (int ct4 = 0; ct4 < 4; ++ct4) s[ct4][r] = __expf(s[ct4][r] - mn);
            rs[r] = (s[0][r] + s[1][r]) + (s[2][r] + s[3][r]);
        }
        #pragma unroll
        for (int off = 1; off < 16; off <<= 1)
            #pragma unroll
            for (int r = 0; r < 4; ++r)
                rs[r] += __shfl_xor(rs[r], off, 64);
        #pragma unroll
        for (int r = 0; r < 4; ++r) l[r] = l[r] * alpha[r] + rs[r];
        #pragma unroll
        for (int ct = 0; ct < 8; ++ct)
            #pragma unroll
            for (int r = 0; r < 4; ++r) o[ct][r] *= alpha[r];

        // P -> bf16, transpose via per-wave LDS (wave-internal, no barrier)
        #pragma unroll
        for (int ct4 = 0; ct4 < 4; ++ct4)
            #pragma unroll
            for (int r = 0; r < 4; ++r)
                Ps[wave][4 * hi + r][ct4 * 16 + lo] = f2bf(s[ct4][r]);

        bf16x8 pa0 = *(const bf16x8*)(&Ps[wave][lo][8 * hi]);
        bf16x8 pa1 = *(const bf16x8*)(&Ps[wave][lo][32 + 8 * hi]);

        #pragma unroll
        for (int ct = 0; ct < 8; ++ct) {
            const unsigned short* vp = vT + ((size_t)b * H_ + ct * 16 + lo) * T_ + kv0 + 8 * hi;
            bf16x8 bv0 = *(const bf16x8*)vp;
            bf16x8 bv1 = *(const bf16x8*)(vp + 32);
            o[ct] = __builtin_amdgcn_mfma_f32_16x16x32_bf16(pa0, bv0, o[ct], 0, 0, 0);
            o[ct] = __builtin_amdgcn_mfma_f32_16x16x32_bf16(pa1, bv1, o[ct], 0, 0, 0);
        }
    }

    // write partial state
    const int slot = b * 288 + slot_prefix(qt) + chunk;
    float* op = Opart + (size_t)slot * 4096 + (size_t)(wave * 16) * 128;
    #pragma unroll
    for (int ct = 0; ct < 8; ++ct)
        #pragma unroll
        for (int r = 0; r < 4; ++r)
            op[(4 * hi + r) * 128 + ct * 16 + lo] = o[ct][r];
    if (lo == 0) {
        #pragma unroll
        for (int r = 0; r < 4; ++r) {
            MLpart[slot * 64 + (wave * 16 + 4 * hi + r) * 2]     = m[r];
            MLpart[slot * 64 + (wave * 16 + 4 * hi + r) * 2 + 1] = l[r];
        }
    }
}

// ---------------------------------------------------------------------------
// Flash pass 2: merge <=8 chunk partials per (b, qt). 512 blocks x 128 thr.
// ---------------------------------------------------------------------------
__launch_bounds__(128)
__global__ void attn2_kernel(const float* __restrict__ Opart,
                             const float* __restrict__ MLpart,
                             float* __restrict__ out) {
    const int bid = blockIdx.x;            // 0..511
    const int b = bid & 7, qt = bid >> 3;
    const int nch = (qt >> 3) + 1;
    const int slot0 = b * 288 + slot_prefix(qt);

    const int tid = threadIdx.x;
    const int row = tid >> 2;              // 0..31
    const int h0  = (tid & 3) * 32;

    float M = -1e30f;
    for (int c = 0; c < nch; ++c)
        M = fmaxf(M, MLpart[(slot0 + c) * 64 + row * 2]);
    float L = 0.f;
    for (int c = 0; c < nch; ++c) {
        float mc = MLpart[(slot0 + c) * 64 + row * 2];
        float lc = MLpart[(slot0 + c) * 64 + row * 2 + 1];
        L += lc * __expf(mc - M);
    }

    float4 acc[8];
    #pragma unroll
    for (int j = 0; j < 8; ++j) acc[j] = float4{0.f, 0.f, 0.f, 0.f};
    for (int c = 0; c < nch; ++c) {
        float wc = __expf(MLpart[(slot0 + c) * 64 + row * 2] - M);
        const float4* src = (const float4*)(Opart + (size_t)(slot0 + c) * 4096 + row * 128 + h0);
        #pragma unroll
        for (int j = 0; j < 8; ++j) {
            float4 v = src[j];
            acc[j].x += wc * v.x; acc[j].y += wc * v.y;
            acc[j].z += wc * v.z; acc[j].w += wc * v.w;
        }
    }
    float inv = 1.f / L;
    float4* dst = (float4*)(out + ((size_t)b * T_ + qt * 32 + row) * H_ + h0);
    #pragma unroll
    for (int j = 0; j < 8; ++j) {
        float4 v = acc[j];
        dst[j] = float4{v.x * inv, v.y * inv, v.z * inv, v.w * inv};
    }
}

extern "C" void kernel_launch(void* const* d_in, const int* in_sizes, int n_in,
                              void* d_out, int out_size, void* d_ws, size_t ws_size,
                              hipStream_t stream) {
    const float* x  = (const float*)d_in[0];
    const float* Wq = (const float*)d_in[1];
    const float* Wk = (const float*)d_in[2];
    const float* Wv = (const float*)d_in[3];
    float* out = (float*)d_out;

    char* ws = (char*)d_ws;
    // layout: Wt | qb | kb | vT | region{ xb  (overlaps)  Opart | MLpart }
    unsigned short* Wt  = (unsigned short*)ws;                         // 0.75 MB
    unsigned short* qbf = (unsigned short*)(ws + (size_t)384 * 1024 * 2);
    unsigned short* kbf = qbf + (size_t)B_ * T_ * H_;
    unsigned short* vTf = kbf + (size_t)B_ * T_ * H_;
    char* region = (char*)(vTf + (size_t)B_ * T_ * H_);
    unsigned short* xb  = (unsigned short*)region;                     // 32 MB (dead after gemm)
    float* Opart  = (float*)region;                                    // 2304*4096*4 = 37.75 MB
    float* MLpart = (float*)(region + (size_t)2304 * 4096 * 4);        // 0.59 MB

    xconv_kernel<<<(B_ * T_ * C_) / (256 * 8), 256, 0, stream>>>(x, xb);
    wconv_kernel<<<(384 * 1024) / 256, 256, 0, stream>>>(Wq, Wk, Wv, Wt);
    gemm_kernel<<<(B_ * T_ / 64) * 4, 256, 0, stream>>>(xb, Wt, qbf, kbf, vTf);
    attn1_kernel<<<B_ * 64 * 8, 128, 0, stream>>>(qbf, kbf, vTf, Opart, MLpart);
    attn2_kernel<<<B_ * 64, 128, 0, stream>>>(Opart, MLpart, out);
}

// Round 3
// 151.027 us; speedup vs baseline: 1.4555x; 1.3347x over previous
//
#include <hip/hip_runtime.h>
#include <hip/hip_bf16.h>

#define B_  8
#define T_  2048
#define C_  1024
#define H_  128

using f32x4  = __attribute__((ext_vector_type(4))) float;
using bf16x8 = __attribute__((ext_vector_type(8))) short;

__device__ __forceinline__ unsigned short f2bf(float f) {
    union { float f; unsigned u; } v; v.f = f;
    unsigned r = v.u + 0x7FFFu + ((v.u >> 16) & 1u);   // RNE
    return (unsigned short)(r >> 16);
}

// DPP cross-lane (VALU-speed, replaces ds_swizzle shuffles)
template<int C>
__device__ __forceinline__ float dppf(float v) {
    return __int_as_float(__builtin_amdgcn_update_dpp(0, __float_as_int(v), C, 0xF, 0xF, true));
}
// 16-lane butterfly reduce: quad xor1, quad xor2, half-mirror, mirror
#define DPPRED_MAX(v) { v = fmaxf(v, dppf<0xB1>(v)); v = fmaxf(v, dppf<0x4E>(v)); \
                        v = fmaxf(v, dppf<0x141>(v)); v = fmaxf(v, dppf<0x140>(v)); }
#define DPPRED_SUM(v) { v = v + dppf<0xB1>(v); v = v + dppf<0x4E>(v); \
                        v = v + dppf<0x141>(v); v = v + dppf<0x140>(v); }

// prefix(qt) = sum_{v=1}^{qt} ceil(v/8)  (chunk-slot prefix sum)
__device__ __forceinline__ int slot_prefix(int qt) {
    int g = qt >> 3, r = qt & 7;
    return 4 * g * (g + 1) + r * (g + 1);
}

// ---------------------------------------------------------------------------
// W{q,k,v} fp32 [1024][128] -> Wt bf16 [384 cols][1024 k], Wq pre-scaled 1/32
// ---------------------------------------------------------------------------
__global__ void wconv_kernel(const float* __restrict__ Wq,
                             const float* __restrict__ Wk,
                             const float* __restrict__ Wv,
                             unsigned short* __restrict__ Wt) {
    int id  = blockIdx.x * 256 + threadIdx.x;
    int col = id % 384;
    int k   = id / 384;
    const float* W = (col < 128) ? Wq : ((col < 256) ? Wk : Wv);
    float v = W[k * H_ + (col & 127)];
    if (col < 128) v *= 0.03125f;   // fold C^-0.5 into Wq (exact pow2)
    Wt[(size_t)col * C_ + k] = f2bf(v);
}

// ---------------------------------------------------------------------------
// Fused projection GEMM: x fp32 [16384][1024] @ Wt^T -> qb,kb bf16; vT[8][128][2048].
// 256 blocks x 512 thr (8 waves). Tile 64 rows x 384 cols; wave w = 64r x 48c
// (B loaded once per block). A converted fp32->bf16, staged in LDS (dbuf),
// x and B register-prefetched one K-step ahead. 1 barrier / K-step.
// ---------------------------------------------------------------------------
__launch_bounds__(512)
__global__ void gemm_kernel(const float* __restrict__ x,
                            const unsigned short* __restrict__ Wt,
                            unsigned short* __restrict__ qb,
                            unsigned short* __restrict__ kb,
                            unsigned short* __restrict__ vT) {
    __shared__ unsigned short As[2][64][40];   // padded: stride 80B, 16B-aligned

    const int tid  = threadIdx.x;
    const int wave = tid >> 6;                 // col group: cols wave*48 ..+47
    const int lane = tid & 63;
    const int lo = lane & 15, hi = lane >> 4;
    const int row0 = blockIdx.x * 64;
    const int srow = tid >> 3;                 // staging: row 0..63
    const int sk4  = (tid & 7) * 4;            // staging: k 0,4,..28

    f32x4 acc[4][3];
    #pragma unroll
    for (int rt = 0; rt < 4; ++rt)
        #pragma unroll
        for (int ct = 0; ct < 3; ++ct)
            acc[rt][ct] = f32x4{0.f, 0.f, 0.f, 0.f};

    // prologue: stage step 0 A, prefetch step 0 B
    {
        float4 f = *(const float4*)(x + (size_t)(row0 + srow) * C_ + sk4);
        unsigned a0 = f2bf(f.x) | ((unsigned)f2bf(f.y) << 16);
        unsigned a1 = f2bf(f.z) | ((unsigned)f2bf(f.w) << 16);
        *(uint2*)&As[0][srow][sk4] = uint2{a0, a1};
    }
    bf16x8 bcur[3];
    #pragma unroll
    for (int ct = 0; ct < 3; ++ct)
        bcur[ct] = *(const bf16x8*)(Wt + (size_t)(wave * 48 + ct * 16 + lo) * C_ + 8 * hi);
    __syncthreads();

    for (int kks = 0; kks < 32; ++kks) {
        const int cur = kks & 1;
        const int kk  = kks * 32;

        float4 fn;
        bf16x8 bnxt[3];
        if (kks < 31) {
            fn = *(const float4*)(x + (size_t)(row0 + srow) * C_ + kk + 32 + sk4);
            #pragma unroll
            for (int ct = 0; ct < 3; ++ct)
                bnxt[ct] = *(const bf16x8*)(Wt + (size_t)(wave * 48 + ct * 16 + lo) * C_ + kk + 32 + 8 * hi);
        }

        bf16x8 af[4];
        #pragma unroll
        for (int rt = 0; rt < 4; ++rt)
            af[rt] = *(const bf16x8*)(&As[cur][rt * 16 + lo][8 * hi]);
        #pragma unroll
        for (int rt = 0; rt < 4; ++rt)
            #pragma unroll
            for (int ct = 0; ct < 3; ++ct)
                acc[rt][ct] = __builtin_amdgcn_mfma_f32_16x16x32_bf16(af[rt], bcur[ct], acc[rt][ct], 0, 0, 0);

        if (kks < 31) {
            unsigned a0 = f2bf(fn.x) | ((unsigned)f2bf(fn.y) << 16);
            unsigned a1 = f2bf(fn.z) | ((unsigned)f2bf(fn.w) << 16);
            *(uint2*)&As[cur ^ 1][srow][sk4] = uint2{a0, a1};
            bcur[0] = bnxt[0]; bcur[1] = bnxt[1]; bcur[2] = bnxt[2];
        }
        __syncthreads();
    }

    #pragma unroll
    for (int ct = 0; ct < 3; ++ct) {
        int col = wave * 48 + ct * 16 + lo;
        int head = col >> 7;
        int h = col & 127;
        #pragma unroll
        for (int rt = 0; rt < 4; ++rt) {
            #pragma unroll
            for (int r = 0; r < 4; ++r) {
                int rg = row0 + rt * 16 + 4 * hi + r;
                unsigned short val = f2bf(acc[rt][ct][r]);
                if (head == 0)      qb[(size_t)rg * H_ + h] = val;
                else if (head == 1) kb[(size_t)rg * H_ + h] = val;
                else {
                    int b = rg >> 11, t = rg & (T_ - 1);
                    vT[((size_t)b * H_ + h) * T_ + t] = val;
                }
            }
        }
    }
}

// ---------------------------------------------------------------------------
// Flash pass 1. Grid 4096 (qt desc outer, chunk, b inner — heavy first, empties
// late). Block = 2 waves, wave owns 16 q-rows; chunk = 256 kv (<=4 KV64 tiles).
// Batched K loads -> QK MFMA; V loads hide under DPP softmax; P via wave-local
// LDS; partial (m,l,O) -> workspace.
// ---------------------------------------------------------------------------
__launch_bounds__(128)
__global__ void attn1_kernel(const unsigned short* __restrict__ qb,
                             const unsigned short* __restrict__ kb,
                             const unsigned short* __restrict__ vT,
                             float* __restrict__ Opart,
                             float* __restrict__ MLpart) {
    __shared__ unsigned short Ps[2][16][72];

    const int tid  = threadIdx.x;
    const int wave = tid >> 6;
    const int lane = tid & 63;
    const int lo = lane & 15, hi = lane >> 4;

    const int bid   = blockIdx.x;
    const int b     = bid & 7;
    const int chunk = (bid >> 3) & 7;
    const int qt    = 63 - (bid >> 6);
    const int nch   = (qt >> 3) + 1;
    if (chunk >= nch) return;

    const int kv_begin = chunk << 8;
    const int lim      = min(kv_begin + 256, (qt + 1) << 5);
    const int ntiles   = (lim - kv_begin + 63) >> 6;
    const size_t bT    = (size_t)b * T_;
    const int qrow0    = (qt << 5) + wave * 16;

    bf16x8 qf[4];
    #pragma unroll
    for (int kc = 0; kc < 4; ++kc)
        qf[kc] = *(const bf16x8*)(qb + (bT + qrow0 + lo) * H_ + kc * 32 + 8 * hi);

    float m[4], l[4];
    f32x4 o[8];
    #pragma unroll
    for (int r = 0; r < 4; ++r) { m[r] = -1e30f; l[r] = 0.f; }
    #pragma unroll
    for (int ct = 0; ct < 8; ++ct) o[ct] = f32x4{0.f, 0.f, 0.f, 0.f};

    for (int t = 0; t < ntiles; ++t) {
        const int kv0 = kv_begin + t * 64;

        // batched K fragment loads (16 x 16B, one latency)
        bf16x8 kf[4][4];
        #pragma unroll
        for (int ct4 = 0; ct4 < 4; ++ct4) {
            const unsigned short* kp = kb + (bT + kv0 + ct4 * 16 + lo) * H_ + 8 * hi;
            #pragma unroll
            for (int kc = 0; kc < 4; ++kc)
                kf[ct4][kc] = *(const bf16x8*)(kp + kc * 32);
        }

        f32x4 s[4];
        #pragma unroll
        for (int ct4 = 0; ct4 < 4; ++ct4) s[ct4] = f32x4{0.f, 0.f, 0.f, 0.f};
        __builtin_amdgcn_s_setprio(1);
        #pragma unroll
        for (int ct4 = 0; ct4 < 4; ++ct4)
            #pragma unroll
            for (int kc = 0; kc < 4; ++kc)
                s[ct4] = __builtin_amdgcn_mfma_f32_16x16x32_bf16(qf[kc], kf[ct4][kc], s[ct4], 0, 0, 0);
        __builtin_amdgcn_s_setprio(0);

        // V loads issued now — latency hides under softmax
        bf16x8 vf[8][2];
        #pragma unroll
        for (int ct = 0; ct < 8; ++ct) {
            const unsigned short* vp = vT + ((size_t)b * H_ + ct * 16 + lo) * T_ + kv0 + 8 * hi;
            vf[ct][0] = *(const bf16x8*)vp;
            vf[ct][1] = *(const bf16x8*)(vp + 32);
        }

        if (kv0 + 63 >= qrow0) {   // tile overlaps this wave's diagonal
            #pragma unroll
            for (int ct4 = 0; ct4 < 4; ++ct4)
                #pragma unroll
                for (int r = 0; r < 4; ++r)
                    if (kv0 + ct4 * 16 + lo > qrow0 + 4 * hi + r) s[ct4][r] = -1e30f;
        }

        // online softmax, DPP reductions (VALU-speed)
        float pm[4], alpha[4], rs[4];
        #pragma unroll
        for (int r = 0; r < 4; ++r) {
            pm[r] = fmaxf(fmaxf(s[0][r], s[1][r]), fmaxf(s[2][r], s[3][r]));
            DPPRED_MAX(pm[r]);
        }
        #pragma unroll
        for (int r = 0; r < 4; ++r) {
            float mn = fmaxf(m[r], pm[r]);
            alpha[r] = __expf(m[r] - mn);
            m[r] = mn;
            #pragma unroll
            for (int ct4 = 0; ct4 < 4; ++ct4) s[ct4][r] = __expf(s[ct4][r] - mn);
            rs[r] = (s[0][r] + s[1][r]) + (s[2][r] + s[3][r]);
            DPPRED_SUM(rs[r]);
            l[r] = l[r] * alpha[r] + rs[r];
        }
        #pragma unroll
        for (int ct = 0; ct < 8; ++ct)
            #pragma unroll
            for (int r = 0; r < 4; ++r) o[ct][r] *= alpha[r];

        // P -> bf16, transpose via per-wave LDS (wave-internal, no barrier)
        #pragma unroll
        for (int ct4 = 0; ct4 < 4; ++ct4)
            #pragma unroll
            for (int r = 0; r < 4; ++r)
                Ps[wave][4 * hi + r][ct4 * 16 + lo] = f2bf(s[ct4][r]);

        bf16x8 pa0 = *(const bf16x8*)(&Ps[wave][lo][8 * hi]);
        bf16x8 pa1 = *(const bf16x8*)(&Ps[wave][lo][32 + 8 * hi]);

        __builtin_amdgcn_s_setprio(1);
        #pragma unroll
        for (int ct = 0; ct < 8; ++ct) {
            o[ct] = __builtin_amdgcn_mfma_f32_16x16x32_bf16(pa0, vf[ct][0], o[ct], 0, 0, 0);
            o[ct] = __builtin_amdgcn_mfma_f32_16x16x32_bf16(pa1, vf[ct][1], o[ct], 0, 0, 0);
        }
        __builtin_amdgcn_s_setprio(0);
    }

    // write partial state
    const int slot = b * 288 + slot_prefix(qt) + chunk;
    float* op = Opart + (size_t)slot * 4096 + (size_t)(wave * 16) * 128;
    #pragma unroll
    for (int ct = 0; ct < 8; ++ct)
        #pragma unroll
        for (int r = 0; r < 4; ++r)
            op[(4 * hi + r) * 128 + ct * 16 + lo] = o[ct][r];
    if (lo == 0) {
        #pragma unroll
        for (int r = 0; r < 4; ++r) {
            MLpart[slot * 64 + (wave * 16 + 4 * hi + r) * 2]     = m[r];
            MLpart[slot * 64 + (wave * 16 + 4 * hi + r) * 2 + 1] = l[r];
        }
    }
}

// ---------------------------------------------------------------------------
// Flash pass 2: merge <=8 chunk partials per (b, qt). 512 blocks x 128 thr.
// ---------------------------------------------------------------------------
__launch_bounds__(128)
__global__ void attn2_kernel(const float* __restrict__ Opart,
                             const float* __restrict__ MLpart,
                             float* __restrict__ out) {
    const int bid = blockIdx.x;            // 0..511
    const int b = bid & 7, qt = bid >> 3;
    const int nch = (qt >> 3) + 1;
    const int slot0 = b * 288 + slot_prefix(qt);

    const int tid = threadIdx.x;
    const int row = tid >> 2;              // 0..31
    const int h0  = (tid & 3) * 32;

    float M = -1e30f;
    for (int c = 0; c < nch; ++c)
        M = fmaxf(M, MLpart[(slot0 + c) * 64 + row * 2]);
    float L = 0.f;
    for (int c = 0; c < nch; ++c) {
        float mc = MLpart[(slot0 + c) * 64 + row * 2];
        float lc = MLpart[(slot0 + c) * 64 + row * 2 + 1];
        L += lc * __expf(mc - M);
    }

    float4 acc[8];
    #pragma unroll
    for (int j = 0; j < 8; ++j) acc[j] = float4{0.f, 0.f, 0.f, 0.f};
    for (int c = 0; c < nch; ++c) {
        float wc = __expf(MLpart[(slot0 + c) * 64 + row * 2] - M);
        const float4* src = (const float4*)(Opart + (size_t)(slot0 + c) * 4096 + row * 128 + h0);
        #pragma unroll
        for (int j = 0; j < 8; ++j) {
            float4 v = src[j];
            acc[j].x += wc * v.x; acc[j].y += wc * v.y;
            acc[j].z += wc * v.z; acc[j].w += wc * v.w;
        }
    }
    float inv = 1.f / L;
    float4* dst = (float4*)(out + ((size_t)b * T_ + qt * 32 + row) * H_ + h0);
    #pragma unroll
    for (int j = 0; j < 8; ++j) {
        float4 v = acc[j];
        dst[j] = float4{v.x * inv, v.y * inv, v.z * inv, v.w * inv};
    }
}

extern "C" void kernel_launch(void* const* d_in, const int* in_sizes, int n_in,
                              void* d_out, int out_size, void* d_ws, size_t ws_size,
                              hipStream_t stream) {
    const float* x  = (const float*)d_in[0];
    const float* Wq = (const float*)d_in[1];
    const float* Wk = (const float*)d_in[2];
    const float* Wv = (const float*)d_in[3];
    float* out = (float*)d_out;

    char* ws = (char*)d_ws;
    unsigned short* Wt  = (unsigned short*)ws;                         // 0.75 MB
    unsigned short* qbf = (unsigned short*)(ws + (size_t)384 * 1024 * 2);
    unsigned short* kbf = qbf + (size_t)B_ * T_ * H_;
    unsigned short* vTf = kbf + (size_t)B_ * T_ * H_;
    float* Opart  = (float*)(vTf + (size_t)B_ * T_ * H_);              // 37.75 MB
    float* MLpart = (float*)((char*)Opart + (size_t)2304 * 4096 * 4);  // 0.59 MB

    wconv_kernel<<<(384 * 1024) / 256, 256, 0, stream>>>(Wq, Wk, Wv, Wt);
    gemm_kernel<<<B_ * T_ / 64, 512, 0, stream>>>(x, Wt, qbf, kbf, vTf);
    attn1_kernel<<<B_ * 64 * 8, 128, 0, stream>>>(qbf, kbf, vTf, Opart, MLpart);
    attn2_kernel<<<B_ * 64, 128, 0, stream>>>(Opart, MLpart, out);
}

// Round 4
// 89.287 us; speedup vs baseline: 2.4620x; 1.6915x over previous
//
#include <hip/hip_runtime.h>
#include <hip/hip_bf16.h>

#define B_  8
#define T_  2048
#define C_  1024
#define H_  128

using f32x4  = __attribute__((ext_vector_type(4))) float;
using bf16x8 = __attribute__((ext_vector_type(8))) short;

__device__ __forceinline__ unsigned short f2bf(float f) {
    union { float f; unsigned u; } v; v.f = f;
    unsigned r = v.u + 0x7FFFu + ((v.u >> 16) & 1u);   // RNE
    return (unsigned short)(r >> 16);
}

// DPP cross-lane reduce within 16-lane rows (VALU-speed)
template<int C>
__device__ __forceinline__ float dppf(float v) {
    return __int_as_float(__builtin_amdgcn_update_dpp(0, __float_as_int(v), C, 0xF, 0xF, true));
}
#define DPPRED_MAX(v) { v = fmaxf(v, dppf<0xB1>(v)); v = fmaxf(v, dppf<0x4E>(v)); \
                        v = fmaxf(v, dppf<0x141>(v)); v = fmaxf(v, dppf<0x140>(v)); }
#define DPPRED_SUM(v) { v = v + dppf<0xB1>(v); v = v + dppf<0x4E>(v); \
                        v = v + dppf<0x141>(v); v = v + dppf<0x140>(v); }

// ---------------------------------------------------------------------------
// W{q,k,v} fp32 [1024][128] -> Wt bf16 [384 cols][1024 k], Wq pre-scaled 1/32
// ---------------------------------------------------------------------------
__global__ void wconv_kernel(const float* __restrict__ Wq,
                             const float* __restrict__ Wk,
                             const float* __restrict__ Wv,
                             unsigned short* __restrict__ Wt) {
    int id  = blockIdx.x * 256 + threadIdx.x;
    int col = id % 384;
    int k   = id / 384;
    const float* W = (col < 128) ? Wq : ((col < 256) ? Wk : Wv);
    float v = W[k * H_ + (col & 127)];
    if (col < 128) v *= 0.03125f;   // fold C^-0.5 into Wq (exact pow2)
    Wt[(size_t)col * C_ + k] = f2bf(v);
}

// ---------------------------------------------------------------------------
// Fused projection GEMM, 3-deep x prefetch. 256 blocks x 512 thr (8 waves).
// Tile 64 rows x 384 cols; wave w = 64r x 48c. A (x fp32->bf16) staged in LDS
// dbuf; x register-prefetched 3 K-steps ahead, B 1 step ahead.
// ---------------------------------------------------------------------------
__launch_bounds__(512, 2)
__global__ void gemm_kernel(const float* __restrict__ x,
                            const unsigned short* __restrict__ Wt,
                            unsigned short* __restrict__ qb,
                            unsigned short* __restrict__ kb,
                            unsigned short* __restrict__ vT) {
    __shared__ unsigned short As[2][64][40];   // padded: stride 80B

    const int tid  = threadIdx.x;
    const int wave = tid >> 6;
    const int lane = tid & 63;
    const int lo = lane & 15, hi = lane >> 4;
    const int row0 = blockIdx.x * 64;
    const int col0 = wave * 48;
    const int srow = tid >> 3;
    const int sk4  = (tid & 7) * 4;

    const float* xbase = x + (size_t)(row0 + srow) * C_ + sk4;

    f32x4 acc[4][3];
    #pragma unroll
    for (int rt = 0; rt < 4; ++rt)
        #pragma unroll
        for (int ct = 0; ct < 3; ++ct)
            acc[rt][ct] = f32x4{0.f, 0.f, 0.f, 0.f};

    // prologue: x 3-deep, B 2 frag-sets
    float4 f0 = *(const float4*)(xbase);
    float4 f1 = *(const float4*)(xbase + 32);
    float4 f2 = *(const float4*)(xbase + 64);
    bf16x8 bc[3], bn[3];
    #pragma unroll
    for (int ct = 0; ct < 3; ++ct) {
        const unsigned short* wp = Wt + (size_t)(col0 + ct * 16 + lo) * C_ + 8 * hi;
        bc[ct] = *(const bf16x8*)(wp);
        bn[ct] = *(const bf16x8*)(wp + 32);
    }
    {
        unsigned a0 = f2bf(f0.x) | ((unsigned)f2bf(f0.y) << 16);
        unsigned a1 = f2bf(f0.z) | ((unsigned)f2bf(f0.w) << 16);
        *(uint2*)&As[0][srow][sk4] = uint2{a0, a1};
    }
    __syncthreads();

    for (int k = 0; k < 32; ++k) {
        const int cur = k & 1;

        float4 fn = f2;
        if (k < 29) fn = *(const float4*)(xbase + (k + 3) * 32);
        bf16x8 b2[3];
        const bool ldb2 = (k < 30);
        if (ldb2) {
            #pragma unroll
            for (int ct = 0; ct < 3; ++ct)
                b2[ct] = *(const bf16x8*)(Wt + (size_t)(col0 + ct * 16 + lo) * C_ + (k + 2) * 32 + 8 * hi);
        }

        bf16x8 af[4];
        #pragma unroll
        for (int rt = 0; rt < 4; ++rt)
            af[rt] = *(const bf16x8*)(&As[cur][rt * 16 + lo][8 * hi]);
        #pragma unroll
        for (int rt = 0; rt < 4; ++rt)
            #pragma unroll
            for (int ct = 0; ct < 3; ++ct)
                acc[rt][ct] = __builtin_amdgcn_mfma_f32_16x16x32_bf16(af[rt], bc[ct], acc[rt][ct], 0, 0, 0);

        if (k < 31) {
            unsigned a0 = f2bf(f1.x) | ((unsigned)f2bf(f1.y) << 16);
            unsigned a1 = f2bf(f1.z) | ((unsigned)f2bf(f1.w) << 16);
            *(uint2*)&As[cur ^ 1][srow][sk4] = uint2{a0, a1};
        }
        __syncthreads();

        f1 = f2; f2 = fn;
        bc[0] = bn[0]; bc[1] = bn[1]; bc[2] = bn[2];
        if (ldb2) { bn[0] = b2[0]; bn[1] = b2[1]; bn[2] = b2[2]; }
    }

    #pragma unroll
    for (int ct = 0; ct < 3; ++ct) {
        int col = col0 + ct * 16 + lo;
        int head = col >> 7;
        int h = col & 127;
        #pragma unroll
        for (int rt = 0; rt < 4; ++rt) {
            #pragma unroll
            for (int r = 0; r < 4; ++r) {
                int rg = row0 + rt * 16 + 4 * hi + r;
                unsigned short val = f2bf(acc[rt][ct][r]);
                if (head == 0)      qb[(size_t)rg * H_ + h] = val;
                else if (head == 1) kb[(size_t)rg * H_ + h] = val;
                else {
                    int b = rg >> 11, t = rg & (T_ - 1);
                    vT[((size_t)b * H_ + h) * T_ + t] = val;
                }
            }
        }
    }
}

// ---------------------------------------------------------------------------
// Flash pass 1. Block = 8 waves (512 thr); QBLK=256 (32 q-rows/wave);
// chunk = 256 kv = 4 x KV64 tiles (always full). Grid 512 (heavy qt first),
// empties exit. K/V tiles staged in XOR-swizzled LDS shared by all 8 waves,
// reg-staged one tile ahead (loads fly under compute). Per-wave guard skips
// fully-masked tiles. Partial (m,l,O) per (b,qt,chunk) slot.
// ---------------------------------------------------------------------------
__launch_bounds__(512, 2)
__global__ void attn1_kernel(const unsigned short* __restrict__ qb,
                             const unsigned short* __restrict__ kb,
                             const unsigned short* __restrict__ vT,
                             float* __restrict__ Opart,
                             float* __restrict__ MLpart) {
    __shared__ unsigned short Ks[64 * 128];   // [kv][k], 16B chunks XOR-swizzled
    __shared__ unsigned short Vs[128 * 64];   // [h][kv], swizzled
    __shared__ unsigned short Ps[8][16][72];  // per-wave P transpose (2-pass)

    const int tid  = threadIdx.x;
    const int wave = tid >> 6;
    const int lane = tid & 63;
    const int lo = lane & 15, hi = lane >> 4;

    const int bid   = blockIdx.x;
    const int b     = bid & 7;
    const int chunk = (bid >> 3) & 7;
    const int qt    = 7 - (bid >> 6);
    if (chunk > qt) return;

    const int kv_begin = chunk << 8;
    const size_t bT = (size_t)b * T_;
    const int qrow0 = (qt << 8) + wave * 32;

    // staging assignment: K 2x16B chunks, V 2x16B chunks per thread
    const int krow = tid >> 3, kcol = (tid & 7) * 2;
    const int vrow = tid >> 2, vcol = (tid & 3) * 2;
    const unsigned short* kgsrc = kb + (bT + krow) * H_ + kcol * 8;
    const unsigned short* vgsrc = vT + ((size_t)b * H_ + vrow) * T_ + vcol * 8;
    unsigned short* kdst0 = &Ks[krow * 128 + ((kcol ^ (krow & 7)) * 8)];
    unsigned short* kdst1 = &Ks[krow * 128 + (((kcol + 1) ^ (krow & 7)) * 8)];
    unsigned short* vdst0 = &Vs[vrow * 64 + ((vcol ^ (vrow & 7)) * 8)];
    unsigned short* vdst1 = &Vs[vrow * 64 + (((vcol + 1) ^ (vrow & 7)) * 8)];

    // Q fragments (32 rows/wave)
    bf16x8 qf[2][4];
    #pragma unroll
    for (int q2 = 0; q2 < 2; ++q2)
        #pragma unroll
        for (int kc = 0; kc < 4; ++kc)
            qf[q2][kc] = *(const bf16x8*)(qb + (bT + qrow0 + 16 * q2 + lo) * H_ + kc * 32 + 8 * hi);

    float m[2][4], l[2][4];
    f32x4 o[2][8];
    #pragma unroll
    for (int q2 = 0; q2 < 2; ++q2)
        #pragma unroll
        for (int r = 0; r < 4; ++r) { m[q2][r] = -1e30f; l[q2][r] = 0.f; }
    #pragma unroll
    for (int q2 = 0; q2 < 2; ++q2)
        #pragma unroll
        for (int ct = 0; ct < 8; ++ct) o[q2][ct] = f32x4{0.f, 0.f, 0.f, 0.f};

    // prologue: stage-regs for tile 0
    uint4 kr0 = *(const uint4*)(kgsrc + (size_t)kv_begin * H_);
    uint4 kr1 = *(const uint4*)(kgsrc + (size_t)kv_begin * H_ + 8);
    uint4 vr0 = *(const uint4*)(vgsrc + kv_begin);
    uint4 vr1 = *(const uint4*)(vgsrc + kv_begin + 8);

    for (int t = 0; t < 4; ++t) {
        const int kv0 = kv_begin + t * 64;
        __syncthreads();                       // all reads of prev tile done
        *(uint4*)kdst0 = kr0;
        *(uint4*)kdst1 = kr1;
        *(uint4*)vdst0 = vr0;
        *(uint4*)vdst1 = vr1;
        __syncthreads();                       // tile staged
        if (t < 3) {                           // issue next-tile loads now
            const int kvn = kv0 + 64;
            kr0 = *(const uint4*)(kgsrc + (size_t)kvn * H_);
            kr1 = *(const uint4*)(kgsrc + (size_t)kvn * H_ + 8);
            vr0 = *(const uint4*)(vgsrc + kvn);
            vr1 = *(const uint4*)(vgsrc + kvn + 8);
        }
        if (kv0 > qrow0 + 31) continue;        // fully masked for this wave

        // S = Q K^T
        f32x4 s[2][4];
        #pragma unroll
        for (int q2 = 0; q2 < 2; ++q2)
            #pragma unroll
            for (int ct4 = 0; ct4 < 4; ++ct4) s[q2][ct4] = f32x4{0.f, 0.f, 0.f, 0.f};
        __builtin_amdgcn_s_setprio(1);
        #pragma unroll
        for (int ct4 = 0; ct4 < 4; ++ct4) {
            const int row = ct4 * 16 + lo;
            #pragma unroll
            for (int kc = 0; kc < 4; ++kc) {
                bf16x8 kf = *(const bf16x8*)&Ks[row * 128 + (((kc * 4 + hi) ^ (row & 7)) * 8)];
                s[0][ct4] = __builtin_amdgcn_mfma_f32_16x16x32_bf16(qf[0][kc], kf, s[0][ct4], 0, 0, 0);
                s[1][ct4] = __builtin_amdgcn_mfma_f32_16x16x32_bf16(qf[1][kc], kf, s[1][ct4], 0, 0, 0);
            }
        }
        __builtin_amdgcn_s_setprio(0);

        // causal mask (diagonal tiles only)
        if (kv0 + 63 >= qrow0) {
            #pragma unroll
            for (int q2 = 0; q2 < 2; ++q2)
                #pragma unroll
                for (int ct4 = 0; ct4 < 4; ++ct4)
                    #pragma unroll
                    for (int r = 0; r < 4; ++r)
                        if (kv0 + ct4 * 16 + lo > qrow0 + 16 * q2 + 4 * hi + r)
                            s[q2][ct4][r] = -1e30f;
        }

        // online softmax (DPP reductions within 16-lane rows)
        float alpha[2][4];
        #pragma unroll
        for (int q2 = 0; q2 < 2; ++q2) {
            #pragma unroll
            for (int r = 0; r < 4; ++r) {
                float pm = fmaxf(fmaxf(s[q2][0][r], s[q2][1][r]), fmaxf(s[q2][2][r], s[q2][3][r]));
                DPPRED_MAX(pm);
                float mn = fmaxf(m[q2][r], pm);
                alpha[q2][r] = __expf(m[q2][r] - mn);
                m[q2][r] = mn;
                #pragma unroll
                for (int ct4 = 0; ct4 < 4; ++ct4) s[q2][ct4][r] = __expf(s[q2][ct4][r] - mn);
                float rs = (s[q2][0][r] + s[q2][1][r]) + (s[q2][2][r] + s[q2][3][r]);
                DPPRED_SUM(rs);
                l[q2][r] = l[q2][r] * alpha[q2][r] + rs;
            }
        }
        #pragma unroll
        for (int q2 = 0; q2 < 2; ++q2)
            #pragma unroll
            for (int ct = 0; ct < 8; ++ct)
                #pragma unroll
                for (int r = 0; r < 4; ++r) o[q2][ct][r] *= alpha[q2][r];

        // P -> bf16, transpose via per-wave LDS (2-pass, wave-internal)
        bf16x8 pa[2][2];
        #pragma unroll
        for (int q2 = 0; q2 < 2; ++q2) {
            #pragma unroll
            for (int ct4 = 0; ct4 < 4; ++ct4)
                #pragma unroll
                for (int r = 0; r < 4; ++r)
                    Ps[wave][4 * hi + r][ct4 * 16 + lo] = f2bf(s[q2][ct4][r]);
            pa[q2][0] = *(const bf16x8*)&Ps[wave][lo][8 * hi];
            pa[q2][1] = *(const bf16x8*)&Ps[wave][lo][32 + 8 * hi];
        }

        // O += P V
        __builtin_amdgcn_s_setprio(1);
        #pragma unroll
        for (int ct = 0; ct < 8; ++ct) {
            const int row = ct * 16 + lo;
            #pragma unroll
            for (int half = 0; half < 2; ++half) {
                bf16x8 vf = *(const bf16x8*)&Vs[row * 64 + (((half * 4 + hi) ^ (row & 7)) * 8)];
                o[0][ct] = __builtin_amdgcn_mfma_f32_16x16x32_bf16(pa[0][half], vf, o[0][ct], 0, 0, 0);
                o[1][ct] = __builtin_amdgcn_mfma_f32_16x16x32_bf16(pa[1][half], vf, o[1][ct], 0, 0, 0);
            }
        }
        __builtin_amdgcn_s_setprio(0);
    }

    // write partial state: slot = b*36 + qt(qt+1)/2 + chunk
    const int slot = b * 36 + ((qt * (qt + 1)) >> 1) + chunk;
    float* op = Opart + (size_t)slot * 32768 + (size_t)(wave * 32) * 128;
    #pragma unroll
    for (int q2 = 0; q2 < 2; ++q2)
        #pragma unroll
        for (int ct = 0; ct < 8; ++ct)
            #pragma unroll
            for (int r = 0; r < 4; ++r)
                op[(16 * q2 + 4 * hi + r) * 128 + ct * 16 + lo] = o[q2][ct][r];
    if (lo == 0) {
        #pragma unroll
        for (int q2 = 0; q2 < 2; ++q2)
            #pragma unroll
            for (int r = 0; r < 4; ++r) {
                int base = slot * 512 + (wave * 32 + 16 * q2 + 4 * hi + r) * 2;
                MLpart[base]     = m[q2][r];
                MLpart[base + 1] = l[q2][r];
            }
    }
}

// ---------------------------------------------------------------------------
// Flash pass 2: merge <= 8 chunk partials. 512 blocks x 128 thr.
// bid -> (b, qt, sub32); each thread: 1 row x 32 cols.
// ---------------------------------------------------------------------------
__launch_bounds__(128)
__global__ void attn2_kernel(const float* __restrict__ Opart,
                             const float* __restrict__ MLpart,
                             float* __restrict__ out) {
    const int bid = blockIdx.x;
    const int b   = bid & 7;
    const int qt  = (bid >> 3) & 7;
    const int sub = bid >> 6;              // 0..7
    const int nch = qt + 1;
    const int slot0 = b * 36 + ((qt * (qt + 1)) >> 1);

    const int tid  = threadIdx.x;
    const int row  = tid >> 2;             // 0..31
    const int h0   = (tid & 3) * 32;
    const int srow = sub * 32 + row;       // row within slot

    float M = -1e30f;
    for (int c = 0; c < nch; ++c)
        M = fmaxf(M, MLpart[(slot0 + c) * 512 + srow * 2]);
    float L = 0.f;
    for (int c = 0; c < nch; ++c) {
        float mc = MLpart[(slot0 + c) * 512 + srow * 2];
        float lc = MLpart[(slot0 + c) * 512 + srow * 2 + 1];
        L += lc * __expf(mc - M);
    }

    float4 acc[8];
    #pragma unroll
    for (int j = 0; j < 8; ++j) acc[j] = float4{0.f, 0.f, 0.f, 0.f};
    for (int c = 0; c < nch; ++c) {
        float wc = __expf(MLpart[(slot0 + c) * 512 + srow * 2] - M);
        const float4* src = (const float4*)(Opart + (size_t)(slot0 + c) * 32768 + (size_t)srow * 128 + h0);
        #pragma unroll
        for (int j = 0; j < 8; ++j) {
            float4 v = src[j];
            acc[j].x += wc * v.x; acc[j].y += wc * v.y;
            acc[j].z += wc * v.z; acc[j].w += wc * v.w;
        }
    }
    float inv = 1.f / L;
    float4* dst = (float4*)(out + ((size_t)b * T_ + qt * 256 + srow) * H_ + h0);
    #pragma unroll
    for (int j = 0; j < 8; ++j) {
        float4 v = acc[j];
        dst[j] = float4{v.x * inv, v.y * inv, v.z * inv, v.w * inv};
    }
}

extern "C" void kernel_launch(void* const* d_in, const int* in_sizes, int n_in,
                              void* d_out, int out_size, void* d_ws, size_t ws_size,
                              hipStream_t stream) {
    const float* x  = (const float*)d_in[0];
    const float* Wq = (const float*)d_in[1];
    const float* Wk = (const float*)d_in[2];
    const float* Wv = (const float*)d_in[3];
    float* out = (float*)d_out;

    char* ws = (char*)d_ws;
    unsigned short* Wt  = (unsigned short*)ws;                          // 0.75 MB
    unsigned short* qbf = (unsigned short*)(ws + (size_t)384 * 1024 * 2);
    unsigned short* kbf = qbf + (size_t)B_ * T_ * H_;
    unsigned short* vTf = kbf + (size_t)B_ * T_ * H_;
    float* Opart  = (float*)(vTf + (size_t)B_ * T_ * H_);               // 288*128KB = 36 MB
    float* MLpart = (float*)((char*)Opart + (size_t)288 * 32768 * 4);   // 0.56 MB

    wconv_kernel<<<(384 * 1024) / 256, 256, 0, stream>>>(Wq, Wk, Wv, Wt);
    gemm_kernel<<<B_ * T_ / 64, 512, 0, stream>>>(x, Wt, qbf, kbf, vTf);
    attn1_kernel<<<512, 512, 0, stream>>>(qbf, kbf, vTf, Opart, MLpart);
    attn2_kernel<<<512, 128, 0, stream>>>(Opart, MLpart, out);
}